// Round 1
// baseline (1148.950 us; speedup 1.0000x reference)
//
#include <hip/hip_runtime.h>
#include <math.h>

// Problem shape (fixed by setup_inputs): B=4, C=2, D=128, H=192, W=192
#define Bq 4
#define Cc 2
#define Dd 128
#define Hh 192
#define Ww 192

constexpr int HW   = Hh * Ww;        // 36864
constexpr int DHW  = Dd * HW;        // 4,718,592
constexpr int CDHW = Cc * DHW;       // 9,437,184
constexpr int NOUT = Bq * DHW;       // 18,874,368 (exactly 73728 * 256)

// logf(1e-7), log1pf(-1e-7) precomputed
#define LOG_EPS       (-16.11809565f)
#define LOG1P_NEG_EPS (-1.00000012e-07f)

__global__ __launch_bounds__(256) void boundary_loss_kernel(
    const float* __restrict__ x,   // inputs  [B,C,D,H,W] f32
    const int*   __restrict__ t,   // targets [B,C,D,H,W] i32 in {0,1}
    float*       __restrict__ out) // scalar accumulator (pre-zeroed)
{
    int idx = blockIdx.x * 256 + threadIdx.x;
    float loss = 0.f;
    if (idx < NOUT) {
        int w = idx % Ww;
        int h = (idx / Ww) % Hh;
        int d = (idx / HW) % Dd;
        int b = idx / DHW;
        bool interior = (d > 0) & (d < Dd - 1) & (h > 0) & (h < Hh - 1)
                      & (w > 0) & (w < Ww - 1);

        int base0 = b * CDHW + d * HW + h * Ww + w;

        // boundary_targets: sum over channels of (t - erode6(t!=0))
        float bt = 0.f;
        #pragma unroll
        for (int c = 0; c < 2; c++) {
            int base = base0 + c * DHW;
            int tv = t[base];
            if (tv != 0) {
                float er = 0.f;
                if (interior) {
                    bool e = (t[base - 1]  != 0) & (t[base + 1]  != 0)
                           & (t[base - Ww] != 0) & (t[base + Ww] != 0)
                           & (t[base - HW] != 0) & (t[base + HW] != 0);
                    er = e ? 1.f : 0.f;
                }
                bt += (float)tv - er;
            }
        }

        if (interior) {
            // boundary_inputs = p0 + p1 - 2 < 0  ->  clipped to eps (constant logs)
            loss = -(bt * LOG_EPS + (1.f - bt) * LOG1P_NEG_EPS);
        } else {
            // border voxel: bi = clip(p0 + p1, eps, 1-eps)
            float x0 = x[base0];
            float x1 = x[base0 + DHW];
            float p0 = 1.f / (1.f + expf(-x0));
            float p1 = 1.f / (1.f + expf(-x1));
            float bi = p0 + p1;
            bi = fminf(fmaxf(bi, 1e-7f), 1.f - 1e-7f);
            loss = -(bt * logf(bi) + (1.f - bt) * log1pf(-bi));
        }
    }

    // wave64 shuffle reduction
    #pragma unroll
    for (int off = 32; off > 0; off >>= 1)
        loss += __shfl_down(loss, off, 64);

    __shared__ float s[4];
    int lane = threadIdx.x & 63;
    int wid  = threadIdx.x >> 6;
    if (lane == 0) s[wid] = loss;
    __syncthreads();
    if (threadIdx.x == 0) {
        float bs = s[0] + s[1] + s[2] + s[3];
        atomicAdd(out, bs * (1.0f / (float)NOUT));
    }
}

extern "C" void kernel_launch(void* const* d_in, const int* in_sizes, int n_in,
                              void* d_out, int out_size, void* d_ws, size_t ws_size,
                              hipStream_t stream) {
    const float* x = (const float*)d_in[0];
    const int*   t = (const int*)d_in[1];
    float* out = (float*)d_out;

    // d_out is re-poisoned to 0xAA before every timed launch — zero it here.
    hipMemsetAsync(out, 0, sizeof(float), stream);

    boundary_loss_kernel<<<NOUT / 256, 256, 0, stream>>>(x, t, out);
}

// Round 2
// 453.894 us; speedup vs baseline: 2.5313x; 2.5313x over previous
//
#include <hip/hip_runtime.h>
#include <math.h>

// Problem shape (fixed by setup_inputs): B=4, C=2, D=128, H=192, W=192
#define Bq 4
#define Dd 128
#define Hh 192
#define Ww 192

constexpr int HW    = Hh * Ww;            // 36864
constexpr int DHW   = Dd * HW;            // 4,718,592
constexpr int CDHW  = 2 * DHW;            // 9,437,184
constexpr int W4    = Ww / 4;             // 48 int4-groups per row
constexpr int NGRP  = Bq * Dd * Hh * W4;  // 4,718,592 threads (4 voxels each)
constexpr long long NOUT = (long long)Bq * DHW; // 18,874,368
constexpr float INV_N = 1.0f / 18874368.0f;

// ln(1e-7) = -16.118095650958319 ; log1p(-1e-7) = -1.00000005e-7
// interior loss (bi clipped to eps) = C0 + C1*bt, with
//   C0 = -log1p(-eps) ; C1 = log1p(-eps) - log(eps)
#define C0f 1.00000005e-07f
#define C1f 16.1180955f

__device__ __forceinline__ float edge_loss(float x0, float x1, float bt) {
    float p0 = 1.f / (1.f + expf(-x0));
    float p1 = 1.f / (1.f + expf(-x1));
    float bi = fminf(fmaxf(p0 + p1, 1e-7f), 1.f - 1e-7f);
    return -(bt * logf(bi) + (1.f - bt) * log1pf(-bi));
}

__global__ __launch_bounds__(256) void boundary_loss_kernel(
    const float* __restrict__ x,   // inputs  [B,2,D,H,W] f32
    const int*   __restrict__ t,   // targets [B,2,D,H,W] i32 in {0,1}
    float*       __restrict__ out) // scalar accumulator (pre-zeroed)
{
    int gid = blockIdx.x * 256 + threadIdx.x;   // one thread = 4 voxels along w
    int w4 = gid % W4;
    int hh = (gid / W4) % Hh;
    int dd = (gid / (W4 * Hh)) % Dd;
    int bb = gid / (W4 * Hh * Dd);
    int w  = w4 * 4;
    int base0 = bb * CDHW + dd * HW + hh * Ww + w;  // channel 0 addr (elements)

    const int4* tp = reinterpret_cast<const int4*>(t);
    int i4 = base0 >> 2;
    int d4 = DHW >> 2;

    // clamped neighbor offsets (clamps only engage on border rows, which
    // never use erosion — values just must be in-bounds)
    int offN = (hh > 0)      ? -(Ww >> 2) : 0;
    int offS = (hh < Hh - 1) ?  (Ww >> 2) : 0;
    int offF = (dd > 0)      ? -(HW >> 2) : 0;
    int offK = (dd < Dd - 1) ?  (HW >> 2) : 0;

    // ---- all target loads issued unconditionally, independent ----
    int4 c0 = tp[i4];            int4 c1 = tp[i4 + d4];
    int4 n0 = tp[i4 + offN];     int4 n1 = tp[i4 + d4 + offN];
    int4 s0 = tp[i4 + offS];     int4 s1 = tp[i4 + d4 + offS];
    int4 f0 = tp[i4 + offF];     int4 f1 = tp[i4 + d4 + offF];
    int4 k0 = tp[i4 + offK];     int4 k1 = tp[i4 + d4 + offK];
    int offL = (w > 0) ? -1 : 0;
    int offR = (w + 4 < Ww) ? 4 : 3;
    int l0 = t[base0 + offL];        int l1 = t[base0 + DHW + offL];
    int r0 = t[base0 + offR];        int r1 = t[base0 + DHW + offR];

    bool rowBorder = (hh == 0) | (hh == Hh - 1) | (dd == 0) | (dd == Dd - 1);

    float loss;
    if (!rowBorder) {
        // erosion per voxel (targets are {0,1} -> bitwise AND)
        int e0_0 = c0.x & l0   & c0.y & n0.x & s0.x & f0.x & k0.x;
        int e0_1 = c0.y & c0.x & c0.z & n0.y & s0.y & f0.y & k0.y;
        int e0_2 = c0.z & c0.y & c0.w & n0.z & s0.z & f0.z & k0.z;
        int e0_3 = c0.w & c0.z & r0   & n0.w & s0.w & f0.w & k0.w;
        int e1_0 = c1.x & l1   & c1.y & n1.x & s1.x & f1.x & k1.x;
        int e1_1 = c1.y & c1.x & c1.z & n1.y & s1.y & f1.y & k1.y;
        int e1_2 = c1.z & c1.y & c1.w & n1.z & s1.z & f1.z & k1.z;
        int e1_3 = c1.w & c1.z & r1   & n1.w & s1.w & f1.w & k1.w;

        int bt0 = c0.x + c1.x - e0_0 - e1_0;
        int bt1 = c0.y + c1.y - e0_1 - e1_1;
        int bt2 = c0.z + c1.z - e0_2 - e1_2;
        int bt3 = c0.w + c1.w - e0_3 - e1_3;

        bool j0b = (w == 0);          // voxel 0 is a w-border voxel
        bool j3b = (w4 == W4 - 1);    // voxel 3 is a w-border voxel
        if (!j0b && !j3b) {
            // all 4 voxels interior: loss linear in bt (bi clipped to eps)
            loss = fmaf((float)(bt0 + bt1 + bt2 + bt3), C1f, 4.f * C0f);
        } else if (j0b) {
            // voxel 0 border (er forced 0 there: bt = c0.x + c1.x)
            int ibt = bt1 + bt2 + bt3;
            loss = fmaf((float)ibt, C1f, 3.f * C0f)
                 + edge_loss(x[base0], x[base0 + DHW], (float)(c0.x + c1.x));
        } else {
            int ibt = bt0 + bt1 + bt2;
            loss = fmaf((float)ibt, C1f, 3.f * C0f)
                 + edge_loss(x[base0 + 3], x[base0 + DHW + 3], (float)(c0.w + c1.w));
        }
    } else {
        // whole row is border: er = 0, bt = c0 + c1, need inputs
        const float4* xp = reinterpret_cast<const float4*>(x);
        float4 xa = xp[i4];
        float4 xb = xp[i4 + d4];
        loss  = edge_loss(xa.x, xb.x, (float)(c0.x + c1.x));
        loss += edge_loss(xa.y, xb.y, (float)(c0.y + c1.y));
        loss += edge_loss(xa.z, xb.z, (float)(c0.z + c1.z));
        loss += edge_loss(xa.w, xb.w, (float)(c0.w + c1.w));
    }

    // wave64 shuffle reduction
    #pragma unroll
    for (int off = 32; off > 0; off >>= 1)
        loss += __shfl_down(loss, off, 64);

    __shared__ float s[4];
    int lane = threadIdx.x & 63;
    int wid  = threadIdx.x >> 6;
    if (lane == 0) s[wid] = loss;
    __syncthreads();
    if (threadIdx.x == 0) {
        float bs = s[0] + s[1] + s[2] + s[3];
        atomicAdd(out, bs * INV_N);
    }
}

extern "C" void kernel_launch(void* const* d_in, const int* in_sizes, int n_in,
                              void* d_out, int out_size, void* d_ws, size_t ws_size,
                              hipStream_t stream) {
    const float* x = (const float*)d_in[0];
    const int*   t = (const int*)d_in[1];
    float* out = (float*)d_out;

    // d_out is re-poisoned to 0xAA before every timed launch — zero it here.
    hipMemsetAsync(out, 0, sizeof(float), stream);

    boundary_loss_kernel<<<NGRP / 256, 256, 0, stream>>>(x, t, out);
}

// Round 3
// 348.935 us; speedup vs baseline: 3.2927x; 1.3008x over previous
//
#include <hip/hip_runtime.h>
#include <math.h>

// Problem shape (fixed by setup_inputs): B=4, C=2, D=128, H=192, W=192
#define Bq 4
#define Dd 128
#define Hh 192
#define Ww 192

constexpr int HW    = Hh * Ww;        // 36864
constexpr int DHW   = Dd * HW;        // 4,718,592
constexpr int CDHW  = 2 * DHW;        // 9,437,184
constexpr int W4    = Ww / 4;         // 48 quads per row
constexpr int ROWS  = 8;              // rows per block
constexpr int BLK   = ROWS * W4;      // 384 threads (6 waves)
constexpr int DSEG  = 16;             // d-planes marched per block
constexpr int NSEG  = Dd / DSEG;      // 8
constexpr int NRG   = Hh / ROWS;      // 24
constexpr float INV_N = 1.0f / 18874368.0f;

// interior loss (bi clipped to eps) = C0 + C1*bt
// C0 = -log1p(-eps) ; C1 = log1p(-eps) - log(eps)
#define C0f 1.00000005e-07f
#define C1f 16.1180955f

__device__ __forceinline__ float edge_loss(float x0, float x1, float bt) {
    float p0 = 1.f / (1.f + expf(-x0));
    float p1 = 1.f / (1.f + expf(-x1));
    float bi = fminf(fmaxf(p0 + p1, 1e-7f), 1.f - 1e-7f);
    return -(bt * logf(bi) + (1.f - bt) * log1pf(-bi));
}

struct PlaneRegs {
    int4 c0, c1, n0, n1, s0, s1;
    int  l0, l1, r0, r1;
};

__global__ __launch_bounds__(BLK) void boundary_loss_kernel(
    const float* __restrict__ x,   // inputs  [B,2,D,H,W] f32
    const int*   __restrict__ t,   // targets [B,2,D,H,W] i32 in {0,1}
    float*       __restrict__ out)
{
    const int tid = threadIdx.x;
    const int q   = tid % W4;          // quad index in row
    const int r   = tid / W4;          // row within rowgroup
    const int hg  = blockIdx.x;        // rowgroup
    const int seg = blockIdx.y;        // d segment
    const int bb  = blockIdx.z;        // batch
    const int h   = hg * ROWS + r;
    const int w   = q * 4;
    const int d0  = seg * DSEG;

    const int planeBase = bb * CDHW + h * Ww + w;  // add d*HW (+DHW for ch1)

    // clamped neighbor offsets (only engaged on border rows, which never
    // use erosion — clamped loads just need to stay in-bounds)
    const int offN = (h > 0)      ? -Ww : 0;
    const int offS = (h < Hh - 1) ?  Ww : 0;
    const int offL = (w > 0)      ? -1  : 0;
    const int offR = (q < W4 - 1) ?  4  : 3;

    const bool hBorder = (h == 0) | (h == Hh - 1);
    const bool qLo = (q == 0), qHi = (q == W4 - 1);

#define LOADP(P, dplane) {                                            \
    int b0_ = planeBase + (dplane) * HW;                              \
    int b1_ = b0_ + DHW;                                              \
    P.c0 = *(const int4*)(t + b0_);                                   \
    P.c1 = *(const int4*)(t + b1_);                                   \
    P.n0 = *(const int4*)(t + b0_ + offN);                            \
    P.n1 = *(const int4*)(t + b1_ + offN);                            \
    P.s0 = *(const int4*)(t + b0_ + offS);                            \
    P.s1 = *(const int4*)(t + b1_ + offS);                            \
    P.l0 = t[b0_ + offL];  P.l1 = t[b1_ + offL];                      \
    P.r0 = t[b0_ + offR];  P.r1 = t[b1_ + offR];                      \
}

    // ---- pipeline preload: z- centers of plane d0-1, full set of d0 ----
    int4 pc0, pc1;
    {
        int dp = (d0 > 0) ? d0 - 1 : 0;     // unused when d==0 (border plane)
        int b0_ = planeBase + dp * HW;
        pc0 = *(const int4*)(t + b0_);
        pc1 = *(const int4*)(t + b0_ + DHW);
    }
    PlaneRegs C; LOADP(C, d0);

    float loss = 0.f;

    #pragma unroll 2
    for (int d = d0; d < d0 + DSEG; ++d) {
        // issue next-plane loads (independent batch; z+ center needed this iter,
        // the rest only next iter)
        int dn = (d < Dd - 1) ? d + 1 : d;  // clamp: unused when d==Dd-1
        PlaneRegs N; LOADP(N, dn);

        bool dBorder = (d == 0) | (d == Dd - 1);
        if (hBorder | dBorder) {
            // entire row is boundary: er=0, bt = t0+t1, need inputs
            int b0_ = planeBase + d * HW;
            float4 xa = *(const float4*)(x + b0_);
            float4 xb = *(const float4*)(x + b0_ + DHW);
            loss += edge_loss(xa.x, xb.x, (float)(C.c0.x + C.c1.x));
            loss += edge_loss(xa.y, xb.y, (float)(C.c0.y + C.c1.y));
            loss += edge_loss(xa.z, xb.z, (float)(C.c0.z + C.c1.z));
            loss += edge_loss(xa.w, xb.w, (float)(C.c0.w + C.c1.w));
        } else {
            // erosion: targets in {0,1} -> bitwise AND of 6 neighbors + self
            int e00 = C.c0.x & C.l0   & C.c0.y & C.n0.x & C.s0.x & pc0.x & N.c0.x;
            int e01 = C.c0.y & C.c0.x & C.c0.z & C.n0.y & C.s0.y & pc0.y & N.c0.y;
            int e02 = C.c0.z & C.c0.y & C.c0.w & C.n0.z & C.s0.z & pc0.z & N.c0.z;
            int e03 = C.c0.w & C.c0.z & C.r0   & C.n0.w & C.s0.w & pc0.w & N.c0.w;
            int e10 = C.c1.x & C.l1   & C.c1.y & C.n1.x & C.s1.x & pc1.x & N.c1.x;
            int e11 = C.c1.y & C.c1.x & C.c1.z & C.n1.y & C.s1.y & pc1.y & N.c1.y;
            int e12 = C.c1.z & C.c1.y & C.c1.w & C.n1.z & C.s1.z & pc1.z & N.c1.z;
            int e13 = C.c1.w & C.c1.z & C.r1   & C.n1.w & C.s1.w & pc1.w & N.c1.w;

            int bt0 = C.c0.x + C.c1.x - e00 - e10;
            int bt1 = C.c0.y + C.c1.y - e01 - e11;
            int bt2 = C.c0.z + C.c1.z - e02 - e12;
            int bt3 = C.c0.w + C.c1.w - e03 - e13;

            if (qLo) {
                // voxel 0 is a w-border voxel: er forced 0, bt = t0+t1
                int b0_ = planeBase + d * HW;
                loss += fmaf((float)(bt1 + bt2 + bt3), C1f, 3.f * C0f)
                      + edge_loss(x[b0_], x[b0_ + DHW], (float)(C.c0.x + C.c1.x));
            } else if (qHi) {
                int b0_ = planeBase + d * HW;
                loss += fmaf((float)(bt0 + bt1 + bt2), C1f, 3.f * C0f)
                      + edge_loss(x[b0_ + 3], x[b0_ + DHW + 3], (float)(C.c0.w + C.c1.w));
            } else {
                loss += fmaf((float)(bt0 + bt1 + bt2 + bt3), C1f, 4.f * C0f);
            }
        }

        // rotate planes
        pc0 = C.c0; pc1 = C.c1;
        C = N;
    }
#undef LOADP

    // wave64 shuffle reduction
    #pragma unroll
    for (int off = 32; off > 0; off >>= 1)
        loss += __shfl_down(loss, off, 64);

    __shared__ float s[BLK / 64];
    int lane = tid & 63;
    int wid  = tid >> 6;
    if (lane == 0) s[wid] = loss;
    __syncthreads();
    if (tid == 0) {
        float bs = 0.f;
        #pragma unroll
        for (int i = 0; i < BLK / 64; i++) bs += s[i];
        atomicAdd(out, bs * INV_N);
    }
}

extern "C" void kernel_launch(void* const* d_in, const int* in_sizes, int n_in,
                              void* d_out, int out_size, void* d_ws, size_t ws_size,
                              hipStream_t stream) {
    const float* x = (const float*)d_in[0];
    const int*   t = (const int*)d_in[1];
    float* out = (float*)d_out;

    hipMemsetAsync(out, 0, sizeof(float), stream);

    dim3 grid(NRG, NSEG, Bq);
    boundary_loss_kernel<<<grid, BLK, 0, stream>>>(x, t, out);
}

// Round 4
// 334.785 us; speedup vs baseline: 3.4319x; 1.0423x over previous
//
#include <hip/hip_runtime.h>
#include <math.h>

// Problem shape (fixed by setup_inputs): B=4, C=2, D=128, H=192, W=192
#define Bq 4
#define Dd 128
#define Hh 192
#define Ww 192

constexpr int HW    = Hh * Ww;        // 36864
constexpr int DHW   = Dd * HW;        // 4,718,592
constexpr int CDHW  = 2 * DHW;        // 9,437,184
constexpr int W4    = Ww / 4;         // 48 quads per row
constexpr int ROWS  = 8;              // rows per block
constexpr int BLK   = ROWS * W4;      // 384 threads (6 waves)
constexpr int DSEG  = 8;              // d-planes marched per block
constexpr int NSEG  = Dd / DSEG;      // 16
constexpr int NRG   = Hh / ROWS;      // 24
constexpr float INV_N = 1.0f / 18874368.0f;

// interior loss (bi clipped to eps) = C0 + C1*bt
#define C0f 1.00000005e-07f
#define C1f 16.1180955f

__device__ __forceinline__ float edge_loss(float x0, float x1, float bt) {
    float p0 = 1.f / (1.f + expf(-x0));
    float p1 = 1.f / (1.f + expf(-x1));
    float bi = fminf(fmaxf(p0 + p1, 1e-7f), 1.f - 1e-7f);
    return -(bt * logf(bi) + (1.f - bt) * log1pf(-bi));
}

struct NSLR { int4 n0, n1, s0, s1; int l0, l1, r0, r1; };

__global__ __launch_bounds__(BLK) void boundary_loss_kernel(
    const float* __restrict__ x,   // inputs  [B,2,D,H,W] f32
    const int*   __restrict__ t,   // targets [B,2,D,H,W] i32 in {0,1}
    float*       __restrict__ out)
{
    const int tid = threadIdx.x;
    const int q   = tid % W4;          // quad index in row
    const int r   = tid / W4;          // row within rowgroup
    const int h   = blockIdx.x * ROWS + r;
    const int d0  = blockIdx.y * DSEG;
    const int bb  = blockIdx.z;
    const int w   = q * 4;

    const int colBase = bb * CDHW + h * Ww + w;  // + d*HW (+DHW for ch1)

    // clamped neighbor offsets (only engaged on border rows, which never
    // use erosion — clamped loads just need in-bounds addresses)
    const int offN = (h > 0)      ? -Ww : 0;
    const int offS = (h < Hh - 1) ?  Ww : 0;
    const int offL = (w > 0)      ? -1  : 0;
    const int offR = (q < W4 - 1) ?  4  : 3;

    const bool hBorder = (h == 0) | (h == Hh - 1);
    const bool qLo = (q == 0), qHi = (q == W4 - 1);

    auto ldc = [&](int d, int4 &a, int4 &b) {
        const int* p = t + colBase + d * HW;
        a = *(const int4*)p;
        b = *(const int4*)(p + DHW);
    };
    auto ldns = [&](int d, NSLR &P) {
        const int* p0 = t + colBase + d * HW;
        const int* p1 = p0 + DHW;
        P.n0 = *(const int4*)(p0 + offN);
        P.n1 = *(const int4*)(p1 + offN);
        P.s0 = *(const int4*)(p0 + offS);
        P.s1 = *(const int4*)(p1 + offS);
        P.l0 = p0[offL];  P.l1 = p1[offL];
        P.r0 = p0[offR];  P.r1 = p1[offR];
    };

    // ---- prologue: centers d0-1 / d0 / d0+1, n-s-l-r of d0 ----
    int4 cm0, cm1, cc0, cc1, cp0, cp1;
    NSLR ns;
    ldc((d0 > 0) ? d0 - 1 : 0, cm0, cm1);   // unused when d0==0 (border plane)
    ldc(d0, cc0, cc1);
    ldns(d0, ns);
    ldc((d0 + 1 < Dd) ? d0 + 1 : Dd - 1, cp0, cp1);

    float loss = 0.f;

    #pragma unroll
    for (int i = 0; i < DSEG; ++i) {
        const int d = d0 + i;
        // issue next-plane batch: n/s/l/r of d+1, centers of d+2.
        // NOTHING in this iteration's compute depends on these loads.
        NSLR nsn; int4 cf0, cf1;
        const int dn1 = (d + 1 < Dd) ? d + 1 : Dd - 1;
        const int dn2 = (d + 2 < Dd) ? d + 2 : Dd - 1;
        ldns(dn1, nsn);
        ldc(dn2, cf0, cf1);

        const bool dBorder = (d == 0) | (d == Dd - 1);
        if (hBorder | dBorder) {
            // entire row is boundary: er=0, bt = t0+t1, need inputs
            const float* xp = x + colBase + d * HW;
            float4 xa = *(const float4*)xp;
            float4 xb = *(const float4*)(xp + DHW);
            loss += edge_loss(xa.x, xb.x, (float)(cc0.x + cc1.x));
            loss += edge_loss(xa.y, xb.y, (float)(cc0.y + cc1.y));
            loss += edge_loss(xa.z, xb.z, (float)(cc0.z + cc1.z));
            loss += edge_loss(xa.w, xb.w, (float)(cc0.w + cc1.w));
        } else {
            // erosion: targets in {0,1} -> bitwise AND of self + 6 neighbors
            int e00 = cc0.x & ns.l0  & cc0.y & ns.n0.x & ns.s0.x & cm0.x & cp0.x;
            int e01 = cc0.y & cc0.x  & cc0.z & ns.n0.y & ns.s0.y & cm0.y & cp0.y;
            int e02 = cc0.z & cc0.y  & cc0.w & ns.n0.z & ns.s0.z & cm0.z & cp0.z;
            int e03 = cc0.w & cc0.z  & ns.r0 & ns.n0.w & ns.s0.w & cm0.w & cp0.w;
            int e10 = cc1.x & ns.l1  & cc1.y & ns.n1.x & ns.s1.x & cm1.x & cp1.x;
            int e11 = cc1.y & cc1.x  & cc1.z & ns.n1.y & ns.s1.y & cm1.y & cp1.y;
            int e12 = cc1.z & cc1.y  & cc1.w & ns.n1.z & ns.s1.z & cm1.z & cp1.z;
            int e13 = cc1.w & cc1.z  & ns.r1 & ns.n1.w & ns.s1.w & cm1.w & cp1.w;

            int bt0 = cc0.x + cc1.x - e00 - e10;
            int bt1 = cc0.y + cc1.y - e01 - e11;
            int bt2 = cc0.z + cc1.z - e02 - e12;
            int bt3 = cc0.w + cc1.w - e03 - e13;

            if (qLo) {
                // voxel 0 is a w-border voxel: er forced 0, bt = t0+t1
                const float* xp = x + colBase + d * HW;
                loss += fmaf((float)(bt1 + bt2 + bt3), C1f, 3.f * C0f)
                      + edge_loss(xp[0], xp[DHW], (float)(cc0.x + cc1.x));
            } else if (qHi) {
                const float* xp = x + colBase + d * HW;
                loss += fmaf((float)(bt0 + bt1 + bt2), C1f, 3.f * C0f)
                      + edge_loss(xp[3], xp[DHW + 3], (float)(cc0.w + cc1.w));
            } else {
                loss += fmaf((float)(bt0 + bt1 + bt2 + bt3), C1f, 4.f * C0f);
            }
        }

        // rotate planes (pure renaming under full unroll)
        cm0 = cc0; cm1 = cc1;
        cc0 = cp0; cc1 = cp1;
        ns  = nsn;
        cp0 = cf0; cp1 = cf1;
    }

    // wave64 shuffle reduction
    #pragma unroll
    for (int off = 32; off > 0; off >>= 1)
        loss += __shfl_down(loss, off, 64);

    __shared__ float s[BLK / 64];
    int lane = tid & 63;
    int wid  = tid >> 6;
    if (lane == 0) s[wid] = loss;
    __syncthreads();
    if (tid == 0) {
        float bs = 0.f;
        #pragma unroll
        for (int i = 0; i < BLK / 64; i++) bs += s[i];
        atomicAdd(out, bs * INV_N);
    }
}

extern "C" void kernel_launch(void* const* d_in, const int* in_sizes, int n_in,
                              void* d_out, int out_size, void* d_ws, size_t ws_size,
                              hipStream_t stream) {
    const float* x = (const float*)d_in[0];
    const int*   t = (const int*)d_in[1];
    float* out = (float*)d_out;

    hipMemsetAsync(out, 0, sizeof(float), stream);

    dim3 grid(NRG, NSEG, Bq);
    boundary_loss_kernel<<<grid, BLK, 0, stream>>>(x, t, out);
}

// Round 5
// 294.973 us; speedup vs baseline: 3.8951x; 1.1350x over previous
//
#include <hip/hip_runtime.h>
#include <math.h>

// Problem shape (fixed by setup_inputs): B=4, C=2, D=128, H=192, W=192
#define Bq 4
#define Dd 128
#define Hh 192
#define Ww 192

typedef unsigned long long ull;

constexpr int HW    = Hh * Ww;        // 36864
constexpr int DHW   = Dd * HW;        // 4,718,592
constexpr int CDHW  = 2 * DHW;        // 9,437,184
constexpr int WPP   = HW / 64;        // 576 packed words per plane
constexpr int WPC   = Dd * WPP;       // 73,728 words per (b,c) volume
constexpr int TOTW  = Bq * 2 * WPC;   // 589,824 words (4.7 MB)
constexpr int TOTV  = TOTW * 64;      // 37,748,736 voxels (both channels)
constexpr float INV_N = 1.0f / 18874368.0f;

// interior loss (bi clipped to eps) = C0 + C1*bt
#define C0f 1.00000005e-07f
#define C1f 16.1180955f

__device__ __forceinline__ float edge_loss(float x0, float x1, float bt) {
    float p0 = 1.f / (1.f + expf(-x0));
    float p1 = 1.f / (1.f + expf(-x1));
    float bi = fminf(fmaxf(p0 + p1, 1e-7f), 1.f - 1e-7f);
    return -(bt * logf(bi) + (1.f - bt) * log1pf(-bi));
}

__device__ __forceinline__ void block_reduce_atomic(float loss, float* out) {
    #pragma unroll
    for (int off = 32; off > 0; off >>= 1)
        loss += __shfl_down(loss, off, 64);
    __shared__ float s[4];
    int lane = threadIdx.x & 63;
    int wid  = threadIdx.x >> 6;
    if (lane == 0) s[wid] = loss;
    __syncthreads();
    if (threadIdx.x == 0)
        atomicAdd(out, (s[0] + s[1] + s[2] + s[3]) * INV_N);
}

// ---------------- Pass 1: pack targets to 1 bit/voxel ----------------
// Each wave packs 4096 consecutive voxels (64 ballots), perfectly coalesced.
__global__ __launch_bounds__(256) void pack_kernel(
    const int* __restrict__ t, ull* __restrict__ packed)
{
    const int lane  = threadIdx.x & 63;
    const int gwave = (blockIdx.x * 256 + threadIdx.x) >> 6;
    const int base  = gwave * 4096;
    const int* p = t + base + lane;
    ull word = 0;
    #pragma unroll
    for (int k = 0; k < 64; ++k) {
        ull bal = __ballot(p[k * 64] != 0);
        if (lane == k) word = bal;
    }
    packed[gwave * 64 + lane] = word;
}

// ---------------- Pass 2: interior rows (d in [1,126], h in [1,190]) ----
// One thread = one row of 192 voxels = 3 packed words per channel.
constexpr int NROWSI = Bq * 126 * 190;   // 95,760

__global__ __launch_bounds__(256) void interior_kernel(
    const float* __restrict__ x, const ull* __restrict__ pk,
    float* __restrict__ out)
{
    int rid = blockIdx.x * 256 + threadIdx.x;
    float loss = 0.f;
    if (rid < NROWSI) {
        int h = 1 + rid % 190;
        int d = 1 + (rid / 190) % 126;
        int b = rid / (190 * 126);

        const ull* q0 = pk + (b * 2) * WPC + d * WPP + h * 3;   // ch0 row
        const ull* q1 = q0 + WPC;                                // ch1 row

        ull c00 = q0[0],   c01 = q0[1],      c02 = q0[2];
        ull n00 = q0[-3],  n01 = q0[-2],     n02 = q0[-1];
        ull s00 = q0[3],   s01 = q0[4],      s02 = q0[5];
        ull f00 = q0[-WPP],f01 = q0[-WPP+1], f02 = q0[-WPP+2];
        ull k00 = q0[WPP], k01 = q0[WPP+1],  k02 = q0[WPP+2];
        ull c10 = q1[0],   c11 = q1[1],      c12 = q1[2];
        ull n10 = q1[-3],  n11 = q1[-2],     n12 = q1[-1];
        ull s10 = q1[3],   s11 = q1[4],      s12 = q1[5];
        ull f10 = q1[-WPP],f11 = q1[-WPP+1], f12 = q1[-WPP+2];
        ull k10 = q1[WPP], k11 = q1[WPP+1],  k12 = q1[WPP+2];

        // left/right neighbor masks via shifts (w-border bits get 0 => er=0 there)
        ull lm00 = c00 << 1, lm01 = (c01 << 1) | (c00 >> 63), lm02 = (c02 << 1) | (c01 >> 63);
        ull rm00 = (c00 >> 1) | (c01 << 63), rm01 = (c01 >> 1) | (c02 << 63), rm02 = c02 >> 1;
        ull lm10 = c10 << 1, lm11 = (c11 << 1) | (c10 >> 63), lm12 = (c12 << 1) | (c11 >> 63);
        ull rm10 = (c10 >> 1) | (c11 << 63), rm11 = (c11 >> 1) | (c12 << 63), rm12 = c12 >> 1;

        ull e00 = c00 & lm00 & rm00 & n00 & s00 & f00 & k00;
        ull e01 = c01 & lm01 & rm01 & n01 & s01 & f01 & k01;
        ull e02 = c02 & lm02 & rm02 & n02 & s02 & f02 & k02;
        ull e10 = c10 & lm10 & rm10 & n10 & s10 & f10 & k10;
        ull e11 = c11 & lm11 & rm11 & n11 & s11 & f11 & k11;
        ull e12 = c12 & lm12 & rm12 & n12 & s12 & f12 & k12;

        int btsum = __popcll(c00) + __popcll(c01) + __popcll(c02)
                  + __popcll(c10) + __popcll(c11) + __popcll(c12)
                  - __popcll(e00) - __popcll(e01) - __popcll(e02)
                  - __popcll(e10) - __popcll(e11) - __popcll(e12);

        int bt_w0   = (int)(c00 & 1)  + (int)(c10 & 1);    // er=0 at w=0 (shift)
        int bt_w191 = (int)(c02 >> 63) + (int)(c12 >> 63); // er=0 at w=191
        int ibt = btsum - bt_w0 - bt_w191;

        int xb = b * CDHW + d * HW + h * Ww;
        loss = fmaf((float)ibt, C1f, 190.f * C0f)
             + edge_loss(x[xb],       x[xb + DHW],       (float)bt_w0)
             + edge_loss(x[xb + 191], x[xb + DHW + 191], (float)bt_w191);
    }
    block_reduce_atomic(loss, out);
}

// ---------------- Pass 3: d-faces and h-faces (full border rows) --------
constexpr int NF1 = Bq * 2 * Hh * 48;    // d=0,127 planes:     73,728 threads
constexpr int NF2 = Bq * 2 * 126 * 48;   // h=0,191, d interior: 48,384 threads
constexpr int NF  = NF1 + NF2;           // 122,112 (x4 voxels each)

__global__ __launch_bounds__(256) void face_kernel(
    const float* __restrict__ x, const ull* __restrict__ pk,
    float* __restrict__ out)
{
    int fid = blockIdx.x * 256 + threadIdx.x;
    float loss = 0.f;
    if (fid < NF) {
        int b, d, h, q;
        if (fid < NF1) {
            q = fid % 48;
            h = (fid / 48) % Hh;
            d = ((fid / (48 * Hh)) & 1) ? Dd - 1 : 0;
            b = fid / (48 * Hh * 2);
        } else {
            int g = fid - NF1;
            q = g % 48;
            d = 1 + (g / 48) % 126;
            h = ((g / (48 * 126)) & 1) ? Hh - 1 : 0;
            b = g / (48 * 126 * 2);
        }
        int v0  = b * CDHW + d * HW + h * Ww + q * 4;          // x addr, ch0
        int vc0 = (b * 2 * Dd + d) * HW + h * Ww + q * 4;      // packed linear, ch0
        float4 xa  = *(const float4*)(x + v0);
        float4 xb4 = *(const float4*)(x + v0 + DHW);
        int sh = vc0 & 63;                                     // q*4 % 64, <= 60
        unsigned bits0 = (unsigned)((pk[vc0 >> 6]         >> sh) & 0xFull);
        unsigned bits1 = (unsigned)((pk[(vc0 >> 6) + WPC] >> sh) & 0xFull);
        loss  = edge_loss(xa.x, xb4.x, (float)(( bits0       & 1) + ( bits1       & 1)));
        loss += edge_loss(xa.y, xb4.y, (float)(((bits0 >> 1) & 1) + ((bits1 >> 1) & 1)));
        loss += edge_loss(xa.z, xb4.z, (float)(((bits0 >> 2) & 1) + ((bits1 >> 2) & 1)));
        loss += edge_loss(xa.w, xb4.w, (float)(((bits0 >> 3) & 1) + ((bits1 >> 3) & 1)));
    }
    block_reduce_atomic(loss, out);
}

extern "C" void kernel_launch(void* const* d_in, const int* in_sizes, int n_in,
                              void* d_out, int out_size, void* d_ws, size_t ws_size,
                              hipStream_t stream) {
    const float* x = (const float*)d_in[0];
    const int*   t = (const int*)d_in[1];
    float* out = (float*)d_out;
    ull* packed = (ull*)d_ws;   // needs TOTW*8 = 4,718,592 bytes of scratch

    hipMemsetAsync(out, 0, sizeof(float), stream);

    pack_kernel<<<TOTV / 16384, 256, 0, stream>>>(t, packed);
    interior_kernel<<<(NROWSI + 255) / 256, 256, 0, stream>>>(x, packed, out);
    face_kernel<<<(NF + 255) / 256, 256, 0, stream>>>(x, packed, out);
}

// Round 6
// 294.706 us; speedup vs baseline: 3.8986x; 1.0009x over previous
//
#include <hip/hip_runtime.h>
#include <math.h>

// Problem shape (fixed by setup_inputs): B=4, C=2, D=128, H=192, W=192
#define Bq 4
#define Dd 128
#define Hh 192
#define Ww 192

typedef unsigned long long ull;

constexpr int HW    = Hh * Ww;        // 36864
constexpr int DHW   = Dd * HW;        // 4,718,592
constexpr int CDHW  = 2 * DHW;        // 9,437,184
constexpr float INV_N = 1.0f / 18874368.0f;

// Interior tiling: d in [1,126] = 18 segs x 7, h in [1,190] = 10 segs x 19
constexpr int DT = 7,  DSEGN = 18;
constexpr int HT = 19, HSEGN = 10;

// interior loss (bi clipped to eps) = C0 + C1*bt
#define C0f 1.00000005e-07f
#define C1f 16.1180955f

__device__ __forceinline__ float edge_loss(float x0, float x1, float bt) {
    float p0 = 1.f / (1.f + expf(-x0));
    float p1 = 1.f / (1.f + expf(-x1));
    float bi = fminf(fmaxf(p0 + p1, 1e-7f), 1.f - 1e-7f);
    return -(bt * logf(bi) + (1.f - bt) * log1pf(-bi));
}

__device__ __forceinline__ void block_reduce_atomic(float loss, float* out) {
    #pragma unroll
    for (int off = 32; off > 0; off >>= 1)
        loss += __shfl_down(loss, off, 64);
    __shared__ float s[4];
    int lane = threadIdx.x & 63;
    int wid  = threadIdx.x >> 6;
    if (lane == 0) s[wid] = loss;
    __syncthreads();
    if (threadIdx.x == 0)
        atomicAdd(out, (s[0] + s[1] + s[2] + s[3]) * INV_N);
}

// ------------- Main kernel: fused pack(LDS) + erode, interior rows -------------
__global__ __launch_bounds__(256) void interior_kernel(
    const float* __restrict__ x,   // inputs  [B,2,D,H,W] f32
    const int*   __restrict__ t,   // targets [B,2,D,H,W] i32 in {0,1}
    float*       __restrict__ out)
{
    const int tid  = threadIdx.x;
    const int hseg = blockIdx.x;
    const int dseg = blockIdx.y;
    const int b    = blockIdx.z;
    const int dlo  = 1 + dseg * DT;   // interior d range [dlo, dlo+DT)
    const int hlo  = 1 + hseg * HT;   // interior h range [hlo, hlo+HT)

    // packed bits for planes [dlo-1, dlo+DT], rows [hlo-1, hlo+HT]
    // [dp][hp][ch][third]  -> 9*21*2*3 = 1134 ull = 9072 B
    __shared__ ull pk[DT + 2][HT + 2][2][3];

    const int wave = tid >> 6, lane = tid & 63;

    // ---- pack phase: 189 row-slots, 6 ballot-words each ----
    for (int rs = wave; rs < (DT + 2) * (HT + 2); rs += 4) {
        int dp = rs / (HT + 2);
        int hp = rs % (HT + 2);
        const int* base = t + b * CDHW + (dlo - 1 + dp) * HW
                            + (hlo - 1 + hp) * Ww + lane;
        // 6 independent coalesced 256B loads, then ballots
        int v0 = base[0],       v1 = base[64],       v2 = base[128];
        int v3 = base[DHW],     v4 = base[DHW + 64], v5 = base[DHW + 128];
        ull b0 = __ballot(v0 != 0);
        ull b1 = __ballot(v1 != 0);
        ull b2 = __ballot(v2 != 0);
        ull b3 = __ballot(v3 != 0);
        ull b4 = __ballot(v4 != 0);
        ull b5 = __ballot(v5 != 0);
        if (lane == 0) {
            pk[dp][hp][0][0] = b0; pk[dp][hp][0][1] = b1; pk[dp][hp][0][2] = b2;
            pk[dp][hp][1][0] = b3; pk[dp][hp][1][1] = b4; pk[dp][hp][1][2] = b5;
        }
    }
    __syncthreads();

    // ---- erode phase: one thread per interior row (DT*HT = 133 rows) ----
    float loss = 0.f;
    if (tid < DT * HT) {
        int di = tid / HT, hi = tid % HT;
        int dp = 1 + di,  hp = 1 + hi;
        int d = dlo + di, h = hlo + hi;

        ull c00 = pk[dp][hp][0][0],   c01 = pk[dp][hp][0][1],   c02 = pk[dp][hp][0][2];
        ull c10 = pk[dp][hp][1][0],   c11 = pk[dp][hp][1][1],   c12 = pk[dp][hp][1][2];
        ull n00 = pk[dp][hp-1][0][0], n01 = pk[dp][hp-1][0][1], n02 = pk[dp][hp-1][0][2];
        ull n10 = pk[dp][hp-1][1][0], n11 = pk[dp][hp-1][1][1], n12 = pk[dp][hp-1][1][2];
        ull s00 = pk[dp][hp+1][0][0], s01 = pk[dp][hp+1][0][1], s02 = pk[dp][hp+1][0][2];
        ull s10 = pk[dp][hp+1][1][0], s11 = pk[dp][hp+1][1][1], s12 = pk[dp][hp+1][1][2];
        ull f00 = pk[dp-1][hp][0][0], f01 = pk[dp-1][hp][0][1], f02 = pk[dp-1][hp][0][2];
        ull f10 = pk[dp-1][hp][1][0], f11 = pk[dp-1][hp][1][1], f12 = pk[dp-1][hp][1][2];
        ull k00 = pk[dp+1][hp][0][0], k01 = pk[dp+1][hp][0][1], k02 = pk[dp+1][hp][0][2];
        ull k10 = pk[dp+1][hp][1][0], k11 = pk[dp+1][hp][1][1], k12 = pk[dp+1][hp][1][2];

        // left/right neighbor masks via shifts (w-border bits get 0)
        ull lm00 = c00 << 1, lm01 = (c01 << 1) | (c00 >> 63), lm02 = (c02 << 1) | (c01 >> 63);
        ull rm00 = (c00 >> 1) | (c01 << 63), rm01 = (c01 >> 1) | (c02 << 63), rm02 = c02 >> 1;
        ull lm10 = c10 << 1, lm11 = (c11 << 1) | (c10 >> 63), lm12 = (c12 << 1) | (c11 >> 63);
        ull rm10 = (c10 >> 1) | (c11 << 63), rm11 = (c11 >> 1) | (c12 << 63), rm12 = c12 >> 1;

        ull e00 = c00 & lm00 & rm00 & n00 & s00 & f00 & k00;
        ull e01 = c01 & lm01 & rm01 & n01 & s01 & f01 & k01;
        ull e02 = c02 & lm02 & rm02 & n02 & s02 & f02 & k02;
        ull e10 = c10 & lm10 & rm10 & n10 & s10 & f10 & k10;
        ull e11 = c11 & lm11 & rm11 & n11 & s11 & f11 & k11;
        ull e12 = c12 & lm12 & rm12 & n12 & s12 & f12 & k12;

        int btsum = __popcll(c00) + __popcll(c01) + __popcll(c02)
                  + __popcll(c10) + __popcll(c11) + __popcll(c12)
                  - __popcll(e00) - __popcll(e01) - __popcll(e02)
                  - __popcll(e10) - __popcll(e11) - __popcll(e12);

        int bt_w0   = (int)(c00 & 1)   + (int)(c10 & 1);    // er=0 at w=0
        int bt_w191 = (int)(c02 >> 63) + (int)(c12 >> 63);  // er=0 at w=191
        int ibt = btsum - bt_w0 - bt_w191;

        int xb = b * CDHW + d * HW + h * Ww;
        loss = fmaf((float)ibt, C1f, 190.f * C0f)
             + edge_loss(x[xb],       x[xb + DHW],       (float)bt_w0)
             + edge_loss(x[xb + 191], x[xb + DHW + 191], (float)bt_w191);
    }
    block_reduce_atomic(loss, out);
}

// ------------- Face kernel: border rows (d=0,127 all h; h=0,191 d in [1,126]) ---
constexpr int NF1 = Bq * 2 * Hh * 48;    // d faces:  73,728 quads
constexpr int NF2 = Bq * 2 * 126 * 48;   // h faces:  48,384 quads
constexpr int NF  = NF1 + NF2;           // 122,112 quads (x4 voxels)

__global__ __launch_bounds__(256) void face_kernel(
    const float* __restrict__ x, const int* __restrict__ t,
    float* __restrict__ out)
{
    int fid = blockIdx.x * 256 + threadIdx.x;
    float loss = 0.f;
    if (fid < NF) {
        int b, d, h, q;
        if (fid < NF1) {
            q = fid % 48;
            h = (fid / 48) % Hh;
            d = ((fid / (48 * Hh)) & 1) ? Dd - 1 : 0;
            b = fid / (48 * Hh * 2);
        } else {
            int g = fid - NF1;
            q = g % 48;
            d = 1 + (g / 48) % 126;
            h = ((g / (48 * 126)) & 1) ? Hh - 1 : 0;
            b = g / (48 * 126 * 2);
        }
        int v0 = b * CDHW + d * HW + h * Ww + q * 4;
        // er=0 on all border voxels: bt = t0 + t1 (targets are {0,1})
        int4 t0 = *(const int4*)(t + v0);
        int4 t1 = *(const int4*)(t + v0 + DHW);
        float4 xa  = *(const float4*)(x + v0);
        float4 xb4 = *(const float4*)(x + v0 + DHW);
        loss  = edge_loss(xa.x, xb4.x, (float)(t0.x + t1.x));
        loss += edge_loss(xa.y, xb4.y, (float)(t0.y + t1.y));
        loss += edge_loss(xa.z, xb4.z, (float)(t0.z + t1.z));
        loss += edge_loss(xa.w, xb4.w, (float)(t0.w + t1.w));
    }
    block_reduce_atomic(loss, out);
}

extern "C" void kernel_launch(void* const* d_in, const int* in_sizes, int n_in,
                              void* d_out, int out_size, void* d_ws, size_t ws_size,
                              hipStream_t stream) {
    const float* x = (const float*)d_in[0];
    const int*   t = (const int*)d_in[1];
    float* out = (float*)d_out;

    hipMemsetAsync(out, 0, sizeof(float), stream);

    dim3 grid(HSEGN, DSEGN, Bq);   // 10 x 18 x 4 = 720 blocks
    interior_kernel<<<grid, 256, 0, stream>>>(x, t, out);
    face_kernel<<<(NF + 255) / 256, 256, 0, stream>>>(x, t, out);
}

// Round 7
// 292.892 us; speedup vs baseline: 3.9228x; 1.0062x over previous
//
#include <hip/hip_runtime.h>
#include <math.h>

// Problem shape (fixed by setup_inputs): B=4, C=2, D=128, H=192, W=192
#define Bq 4
#define Dd 128
#define Hh 192
#define Ww 192

typedef unsigned long long ull;

constexpr int HW    = Hh * Ww;        // 36864
constexpr int DHW   = Dd * HW;        // 4,718,592
constexpr int CDHW  = 2 * DHW;        // 9,437,184
constexpr int WPR   = 3;              // packed words per row (192/64)
constexpr int WPP   = Hh * WPR;       // 576 words per plane
constexpr int WPC   = Dd * WPP;       // 73,728 words per (b,c) volume
constexpr int TOTW  = Bq * 2 * WPC;   // 589,824 words (4.7 MB)
constexpr int NPKB  = TOTW * 8;       // 4,718,592 byte-pack tasks
constexpr float INV_N = 1.0f / 18874368.0f;

// Interior tiling: d in [1,126] = 18 segs x 7, h in [1,190] = 10 segs x 19
constexpr int DT = 7,  DSEGN = 18;
constexpr int HT = 19, HSEGN = 10;

// interior loss (bi clipped to eps) = C0 + C1*bt
#define C0f 1.00000005e-07f
#define C1f 16.1180955f

__device__ __forceinline__ float edge_loss(float x0, float x1, float bt) {
    float p0 = 1.f / (1.f + expf(-x0));
    float p1 = 1.f / (1.f + expf(-x1));
    float bi = fminf(fmaxf(p0 + p1, 1e-7f), 1.f - 1e-7f);
    return -(bt * logf(bi) + (1.f - bt) * log1pf(-bi));
}

__device__ __forceinline__ void block_reduce_atomic(float loss, float* out) {
    #pragma unroll
    for (int off = 32; off > 0; off >>= 1)
        loss += __shfl_down(loss, off, 64);
    __shared__ float s[4];
    int lane = threadIdx.x & 63;
    int wid  = threadIdx.x >> 6;
    if (lane == 0) s[wid] = loss;
    __syncthreads();
    if (threadIdx.x == 0)
        atomicAdd(out, (s[0] + s[1] + s[2] + s[3]) * INV_N);
}

// ---------- Pass 1: m13-style streaming pack, 8 voxels -> 1 byte ----------
// No ballots, no LDS, no barriers: 2 independent dwordx4 loads + 1 byte store
// per thread. Targets are {0,1} so packing is pure OR/shift.
__global__ __launch_bounds__(256) void pack_kernel(
    const int* __restrict__ t, unsigned char* __restrict__ pk)
{
    int i = blockIdx.x * 256 + threadIdx.x;     // byte index
    const int4* p = reinterpret_cast<const int4*>(t) + (i << 1);
    int4 a = p[0];
    int4 b = p[1];
    unsigned byte = (unsigned)a.x | ((unsigned)a.y << 1) | ((unsigned)a.z << 2)
                  | ((unsigned)a.w << 3) | ((unsigned)b.x << 4)
                  | ((unsigned)b.y << 5) | ((unsigned)b.z << 6)
                  | ((unsigned)b.w << 7);
    pk[i] = (unsigned char)byte;
}

// ---------- Pass 2: LDS-tiled erosion from the packed bit-volume ----------
__global__ __launch_bounds__(256) void interior_kernel(
    const float* __restrict__ x,   // inputs  [B,2,D,H,W] f32
    const ull*   __restrict__ pkw, // packed bits, word-per-64-voxels
    float*       __restrict__ out)
{
    const int tid  = threadIdx.x;
    const int hseg = blockIdx.x;
    const int dseg = blockIdx.y;
    const int b    = blockIdx.z;
    const int dlo  = 1 + dseg * DT;
    const int hlo  = 1 + hseg * HT;

    // packed tile: planes [dlo-1, dlo+DT], rows [hlo-1, hlo+HT]
    __shared__ ull pk[DT + 2][HT + 2][2][3];   // 1134 ull = 9072 B

    // ---- tile load: 1134 words from the 4.7 MB packed buffer (L2/L3) ----
    constexpr int NW = (DT + 2) * (HT + 2) * 2 * 3;
    for (int ws = tid; ws < NW; ws += 256) {
        int j  = ws % 3;
        int c  = (ws / 3) & 1;
        int rp = ws / 6;
        int hp = rp % (HT + 2);
        int dp = rp / (HT + 2);
        pk[dp][hp][c][j] = pkw[(b * 2 + c) * WPC + (dlo - 1 + dp) * WPP
                               + (hlo - 1 + hp) * WPR + j];
    }
    __syncthreads();

    // ---- erode phase: one thread per interior row (DT*HT = 133 rows) ----
    float loss = 0.f;
    if (tid < DT * HT) {
        int di = tid / HT, hi = tid % HT;
        int dp = 1 + di,  hp = 1 + hi;
        int d = dlo + di, h = hlo + hi;

        ull c00 = pk[dp][hp][0][0],   c01 = pk[dp][hp][0][1],   c02 = pk[dp][hp][0][2];
        ull c10 = pk[dp][hp][1][0],   c11 = pk[dp][hp][1][1],   c12 = pk[dp][hp][1][2];
        ull n00 = pk[dp][hp-1][0][0], n01 = pk[dp][hp-1][0][1], n02 = pk[dp][hp-1][0][2];
        ull n10 = pk[dp][hp-1][1][0], n11 = pk[dp][hp-1][1][1], n12 = pk[dp][hp-1][1][2];
        ull s00 = pk[dp][hp+1][0][0], s01 = pk[dp][hp+1][0][1], s02 = pk[dp][hp+1][0][2];
        ull s10 = pk[dp][hp+1][1][0], s11 = pk[dp][hp+1][1][1], s12 = pk[dp][hp+1][1][2];
        ull f00 = pk[dp-1][hp][0][0], f01 = pk[dp-1][hp][0][1], f02 = pk[dp-1][hp][0][2];
        ull f10 = pk[dp-1][hp][1][0], f11 = pk[dp-1][hp][1][1], f12 = pk[dp-1][hp][1][2];
        ull k00 = pk[dp+1][hp][0][0], k01 = pk[dp+1][hp][0][1], k02 = pk[dp+1][hp][0][2];
        ull k10 = pk[dp+1][hp][1][0], k11 = pk[dp+1][hp][1][1], k12 = pk[dp+1][hp][1][2];

        // left/right neighbor masks via shifts (w-border bits get 0)
        ull lm00 = c00 << 1, lm01 = (c01 << 1) | (c00 >> 63), lm02 = (c02 << 1) | (c01 >> 63);
        ull rm00 = (c00 >> 1) | (c01 << 63), rm01 = (c01 >> 1) | (c02 << 63), rm02 = c02 >> 1;
        ull lm10 = c10 << 1, lm11 = (c11 << 1) | (c10 >> 63), lm12 = (c12 << 1) | (c11 >> 63);
        ull rm10 = (c10 >> 1) | (c11 << 63), rm11 = (c11 >> 1) | (c12 << 63), rm12 = c12 >> 1;

        ull e00 = c00 & lm00 & rm00 & n00 & s00 & f00 & k00;
        ull e01 = c01 & lm01 & rm01 & n01 & s01 & f01 & k01;
        ull e02 = c02 & lm02 & rm02 & n02 & s02 & f02 & k02;
        ull e10 = c10 & lm10 & rm10 & n10 & s10 & f10 & k10;
        ull e11 = c11 & lm11 & rm11 & n11 & s11 & f11 & k11;
        ull e12 = c12 & lm12 & rm12 & n12 & s12 & f12 & k12;

        int btsum = __popcll(c00) + __popcll(c01) + __popcll(c02)
                  + __popcll(c10) + __popcll(c11) + __popcll(c12)
                  - __popcll(e00) - __popcll(e01) - __popcll(e02)
                  - __popcll(e10) - __popcll(e11) - __popcll(e12);

        int bt_w0   = (int)(c00 & 1)   + (int)(c10 & 1);    // er=0 at w=0
        int bt_w191 = (int)(c02 >> 63) + (int)(c12 >> 63);  // er=0 at w=191
        int ibt = btsum - bt_w0 - bt_w191;

        int xb = b * CDHW + d * HW + h * Ww;
        loss = fmaf((float)ibt, C1f, 190.f * C0f)
             + edge_loss(x[xb],       x[xb + DHW],       (float)bt_w0)
             + edge_loss(x[xb + 191], x[xb + DHW + 191], (float)bt_w191);
    }
    block_reduce_atomic(loss, out);
}

// ------- Pass 3: border rows (d=0,127 all h; h=0,191 d in [1,126]) --------
constexpr int NF1 = Bq * 2 * Hh * 48;    // d faces:  73,728 quads
constexpr int NF2 = Bq * 2 * 126 * 48;   // h faces:  48,384 quads
constexpr int NF  = NF1 + NF2;           // 122,112 quads (x4 voxels)

__global__ __launch_bounds__(256) void face_kernel(
    const float* __restrict__ x, const int* __restrict__ t,
    float* __restrict__ out)
{
    int fid = blockIdx.x * 256 + threadIdx.x;
    float loss = 0.f;
    if (fid < NF) {
        int b, d, h, q;
        if (fid < NF1) {
            q = fid % 48;
            h = (fid / 48) % Hh;
            d = ((fid / (48 * Hh)) & 1) ? Dd - 1 : 0;
            b = fid / (48 * Hh * 2);
        } else {
            int g = fid - NF1;
            q = g % 48;
            d = 1 + (g / 48) % 126;
            h = ((g / (48 * 126)) & 1) ? Hh - 1 : 0;
            b = g / (48 * 126 * 2);
        }
        int v0 = b * CDHW + d * HW + h * Ww + q * 4;
        // er=0 on all border voxels: bt = t0 + t1 (targets are {0,1})
        int4 t0 = *(const int4*)(t + v0);
        int4 t1 = *(const int4*)(t + v0 + DHW);
        float4 xa  = *(const float4*)(x + v0);
        float4 xb4 = *(const float4*)(x + v0 + DHW);
        loss  = edge_loss(xa.x, xb4.x, (float)(t0.x + t1.x));
        loss += edge_loss(xa.y, xb4.y, (float)(t0.y + t1.y));
        loss += edge_loss(xa.z, xb4.z, (float)(t0.z + t1.z));
        loss += edge_loss(xa.w, xb4.w, (float)(t0.w + t1.w));
    }
    block_reduce_atomic(loss, out);
}

extern "C" void kernel_launch(void* const* d_in, const int* in_sizes, int n_in,
                              void* d_out, int out_size, void* d_ws, size_t ws_size,
                              hipStream_t stream) {
    const float* x = (const float*)d_in[0];
    const int*   t = (const int*)d_in[1];
    float* out = (float*)d_out;
    unsigned char* pkb = (unsigned char*)d_ws;   // 4,718,592 B of scratch
    const ull* pkw = (const ull*)d_ws;

    hipMemsetAsync(out, 0, sizeof(float), stream);

    pack_kernel<<<NPKB / 256, 256, 0, stream>>>(t, pkb);
    dim3 grid(HSEGN, DSEGN, Bq);   // 10 x 18 x 4 = 720 blocks
    interior_kernel<<<grid, 256, 0, stream>>>(x, pkw, out);
    face_kernel<<<(NF + 255) / 256, 256, 0, stream>>>(x, t, out);
}

// Round 8
// 287.572 us; speedup vs baseline: 3.9954x; 1.0185x over previous
//
#include <hip/hip_runtime.h>
#include <math.h>

// Problem shape (fixed by setup_inputs): B=4, C=2, D=128, H=192, W=192
#define Bq 4
#define Dd 128
#define Hh 192
#define Ww 192

typedef unsigned long long ull;

constexpr int HW    = Hh * Ww;        // 36864
constexpr int DHW   = Dd * HW;        // 4,718,592
constexpr int CDHW  = 2 * DHW;        // 9,437,184
constexpr float INV_N = 1.0f / 18874368.0f;

// Interior tiling: d in [1,126] = 18 segs x 7, h in [1,190] = 10 segs x 19
constexpr int DT = 7,  DSEGN = 18;
constexpr int HT = 19, HSEGN = 10;
constexpr int NTILE = HSEGN * DSEGN * Bq;   // 720 interior blocks

// Face work: border rows (d=0,127 all h; h=0,191 d in [1,126])
constexpr int NF1 = Bq * 2 * Hh * 48;    // d faces:  73,728 quads
constexpr int NF2 = Bq * 2 * 126 * 48;   // h faces:  48,384 quads
constexpr int NF  = NF1 + NF2;           // 122,112 quads = 477 * 256 exactly
constexpr int NFBLK = NF / 256;          // 477 face blocks

// interior loss (bi clipped to eps) = C0 + C1*bt
#define C0f 1.00000005e-07f
#define C1f 16.1180955f

__device__ __forceinline__ float edge_loss(float x0, float x1, float bt) {
    float p0 = 1.f / (1.f + expf(-x0));
    float p1 = 1.f / (1.f + expf(-x1));
    float bi = fminf(fmaxf(p0 + p1, 1e-7f), 1.f - 1e-7f);
    return -(bt * logf(bi) + (1.f - bt) * log1pf(-bi));
}

__device__ __forceinline__ void block_reduce_atomic(float loss, float* out) {
    #pragma unroll
    for (int off = 32; off > 0; off >>= 1)
        loss += __shfl_down(loss, off, 64);
    __shared__ float s[4];
    int lane = threadIdx.x & 63;
    int wid  = threadIdx.x >> 6;
    if (lane == 0) s[wid] = loss;
    __syncthreads();
    if (threadIdx.x == 0)
        atomicAdd(out, (s[0] + s[1] + s[2] + s[3]) * INV_N);
}

// One kernel, heterogeneous grid: blocks [0,720) = interior tiles,
// blocks [720, 1197) = face quads.
__global__ __launch_bounds__(256) void boundary_loss_kernel(
    const float* __restrict__ x,   // inputs  [B,2,D,H,W] f32
    const int*   __restrict__ t,   // targets [B,2,D,H,W] i32 in {0,1}
    float*       __restrict__ out)
{
    const int tid = threadIdx.x;

    if (blockIdx.x >= NTILE) {
        // ---------------- face path ----------------
        int fid = (blockIdx.x - NTILE) * 256 + tid;
        float loss = 0.f;
        {
            int b, d, h, q;
            if (fid < NF1) {
                q = fid % 48;
                h = (fid / 48) % Hh;
                d = ((fid / (48 * Hh)) & 1) ? Dd - 1 : 0;
                b = fid / (48 * Hh * 2);
            } else {
                int g = fid - NF1;
                q = g % 48;
                d = 1 + (g / 48) % 126;
                h = ((g / (48 * 126)) & 1) ? Hh - 1 : 0;
                b = g / (48 * 126 * 2);
            }
            int v0 = b * CDHW + d * HW + h * Ww + q * 4;
            // er=0 on all border voxels: bt = t0 + t1 (targets are {0,1})
            int4 t0 = *(const int4*)(t + v0);
            int4 t1 = *(const int4*)(t + v0 + DHW);
            float4 xa  = *(const float4*)(x + v0);
            float4 xb4 = *(const float4*)(x + v0 + DHW);
            loss  = edge_loss(xa.x, xb4.x, (float)(t0.x + t1.x));
            loss += edge_loss(xa.y, xb4.y, (float)(t0.y + t1.y));
            loss += edge_loss(xa.z, xb4.z, (float)(t0.z + t1.z));
            loss += edge_loss(xa.w, xb4.w, (float)(t0.w + t1.w));
        }
        block_reduce_atomic(loss, out);
        return;
    }

    // ---------------- interior tile path ----------------
    const int hseg = blockIdx.x % HSEGN;
    const int dseg = (blockIdx.x / HSEGN) % DSEGN;
    const int b    = blockIdx.x / (HSEGN * DSEGN);
    const int dlo  = 1 + dseg * DT;
    const int hlo  = 1 + hseg * HT;

    // packed tile: planes [dlo-1, dlo+DT], rows [hlo-1, hlo+HT]
    __shared__ ull pk[DT + 2][HT + 2][2][3];   // 1134 ull = 9072 B

    const int wave = tid >> 6, lane = tid & 63;

    // ---- pack phase: 189 row-slots, 48 per wave (padded), unroll 8 so
    // ~48 loads from 8 slots are in flight before their ballots consume
    // them (kills the per-slot full-latency exposure) ----
    #pragma unroll 8
    for (int k = 0; k < 48; ++k) {
        int rs = wave * 48 + k;
        if (rs > (DT + 2) * (HT + 2) - 1) rs = (DT + 2) * (HT + 2) - 1; // benign rewrite
        int dp = rs / (HT + 2);
        int hp = rs % (HT + 2);
        const int* base = t + b * CDHW + (dlo - 1 + dp) * HW
                            + (hlo - 1 + hp) * Ww + lane;
        int v0 = base[0],   v1 = base[64],       v2 = base[128];
        int v3 = base[DHW], v4 = base[DHW + 64], v5 = base[DHW + 128];
        ull b0 = __ballot(v0 != 0);
        ull b1 = __ballot(v1 != 0);
        ull b2 = __ballot(v2 != 0);
        ull b3 = __ballot(v3 != 0);
        ull b4 = __ballot(v4 != 0);
        ull b5 = __ballot(v5 != 0);
        if (lane == 0) {
            pk[dp][hp][0][0] = b0; pk[dp][hp][0][1] = b1; pk[dp][hp][0][2] = b2;
            pk[dp][hp][1][0] = b3; pk[dp][hp][1][1] = b4; pk[dp][hp][1][2] = b5;
        }
    }

    // ---- issue the scattered x-edge loads BEFORE the barrier ----
    float xe0 = 0.f, xe1 = 0.f, xe2 = 0.f, xe3 = 0.f;
    int d = 0, h = 0;
    if (tid < DT * HT) {
        int di = tid / HT, hi = tid % HT;
        d = dlo + di; h = hlo + hi;
        int xb = b * CDHW + d * HW + h * Ww;
        xe0 = x[xb];       xe1 = x[xb + DHW];
        xe2 = x[xb + 191]; xe3 = x[xb + DHW + 191];
    }
    __syncthreads();

    // ---- erode phase: one thread per interior row (DT*HT = 133 rows) ----
    float loss = 0.f;
    if (tid < DT * HT) {
        int di = tid / HT, hi = tid % HT;
        int dp = 1 + di,  hp = 1 + hi;

        ull c00 = pk[dp][hp][0][0],   c01 = pk[dp][hp][0][1],   c02 = pk[dp][hp][0][2];
        ull c10 = pk[dp][hp][1][0],   c11 = pk[dp][hp][1][1],   c12 = pk[dp][hp][1][2];
        ull n00 = pk[dp][hp-1][0][0], n01 = pk[dp][hp-1][0][1], n02 = pk[dp][hp-1][0][2];
        ull n10 = pk[dp][hp-1][1][0], n11 = pk[dp][hp-1][1][1], n12 = pk[dp][hp-1][1][2];
        ull s00 = pk[dp][hp+1][0][0], s01 = pk[dp][hp+1][0][1], s02 = pk[dp][hp+1][0][2];
        ull s10 = pk[dp][hp+1][1][0], s11 = pk[dp][hp+1][1][1], s12 = pk[dp][hp+1][1][2];
        ull f00 = pk[dp-1][hp][0][0], f01 = pk[dp-1][hp][0][1], f02 = pk[dp-1][hp][0][2];
        ull f10 = pk[dp-1][hp][1][0], f11 = pk[dp-1][hp][1][1], f12 = pk[dp-1][hp][1][2];
        ull k00 = pk[dp+1][hp][0][0], k01 = pk[dp+1][hp][0][1], k02 = pk[dp+1][hp][0][2];
        ull k10 = pk[dp+1][hp][1][0], k11 = pk[dp+1][hp][1][1], k12 = pk[dp+1][hp][1][2];

        // left/right neighbor masks via shifts (w-border bits get 0)
        ull lm00 = c00 << 1, lm01 = (c01 << 1) | (c00 >> 63), lm02 = (c02 << 1) | (c01 >> 63);
        ull rm00 = (c00 >> 1) | (c01 << 63), rm01 = (c01 >> 1) | (c02 << 63), rm02 = c02 >> 1;
        ull lm10 = c10 << 1, lm11 = (c11 << 1) | (c10 >> 63), lm12 = (c12 << 1) | (c11 >> 63);
        ull rm10 = (c10 >> 1) | (c11 << 63), rm11 = (c11 >> 1) | (c12 << 63), rm12 = c12 >> 1;

        ull e00 = c00 & lm00 & rm00 & n00 & s00 & f00 & k00;
        ull e01 = c01 & lm01 & rm01 & n01 & s01 & f01 & k01;
        ull e02 = c02 & lm02 & rm02 & n02 & s02 & f02 & k02;
        ull e10 = c10 & lm10 & rm10 & n10 & s10 & f10 & k10;
        ull e11 = c11 & lm11 & rm11 & n11 & s11 & f11 & k11;
        ull e12 = c12 & lm12 & rm12 & n12 & s12 & f12 & k12;

        int btsum = __popcll(c00) + __popcll(c01) + __popcll(c02)
                  + __popcll(c10) + __popcll(c11) + __popcll(c12)
                  - __popcll(e00) - __popcll(e01) - __popcll(e02)
                  - __popcll(e10) - __popcll(e11) - __popcll(e12);

        int bt_w0   = (int)(c00 & 1)   + (int)(c10 & 1);    // er=0 at w=0
        int bt_w191 = (int)(c02 >> 63) + (int)(c12 >> 63);  // er=0 at w=191
        int ibt = btsum - bt_w0 - bt_w191;

        loss = fmaf((float)ibt, C1f, 190.f * C0f)
             + edge_loss(xe0, xe1, (float)bt_w0)
             + edge_loss(xe2, xe3, (float)bt_w191);
    }
    block_reduce_atomic(loss, out);
}

extern "C" void kernel_launch(void* const* d_in, const int* in_sizes, int n_in,
                              void* d_out, int out_size, void* d_ws, size_t ws_size,
                              hipStream_t stream) {
    const float* x = (const float*)d_in[0];
    const int*   t = (const int*)d_in[1];
    float* out = (float*)d_out;

    hipMemsetAsync(out, 0, sizeof(float), stream);

    boundary_loss_kernel<<<NTILE + NFBLK, 256, 0, stream>>>(x, t, out);
}